// Round 10
// baseline (129.625 us; speedup 1.0000x reference)
//
#include <hip/hip_runtime.h>
#include <stdint.h>

// Problem constants
#define N_TOK 16384
#define FEAT  256
#define EMB   128
#define NQ    11   // 10 sinc-quadrature nodes (t_q=e^{-10.8+0.9q}, q=0..9) + 1 analytic t=0 tail
#define KC    16   // K-chunks in k2a: 1024 tokens each.

typedef float  f32x4  __attribute__((ext_vector_type(4)));
typedef __bf16 bf16x8 __attribute__((ext_vector_type(8)));
typedef short  s16x8  __attribute__((ext_vector_type(8)));
typedef unsigned int u32x4 __attribute__((ext_vector_type(4)));

__device__ __forceinline__ unsigned short bf16_rne(float f) {
    union { float f; unsigned u; } v; v.f = f;
    unsigned u = v.u;
    return (unsigned short)((u + 0x7FFFu + ((u >> 16) & 1u)) >> 16);
}
__device__ __forceinline__ float bf16_to_f32(unsigned short s) {
    union { unsigned u; float f; } v; v.u = ((unsigned)s) << 16; return v.f;
}
// pack two f32 -> (bf16(a) | bf16(b)<<16) by truncation; bias ~2^-9 rel
__device__ __forceinline__ unsigned pack_trunc(float a, float b) {
    union { float f; unsigned u; } ua, ub; ua.f = a; ub.f = b;
    return (ub.u & 0xFFFF0000u) | (ua.u >> 16);
}
// pack two f32 -> bf16 pair with RNE (used where values feed many downstream MFMAs)
__device__ __forceinline__ unsigned pack_rne(float a, float b) {
    return (unsigned)bf16_rne(a) | ((unsigned)bf16_rne(b) << 16);
}
__device__ __forceinline__ void async_cp16(const void* g, void* l) {
    __builtin_amdgcn_global_load_lds(
        (const __attribute__((address_space(1))) unsigned int*)g,
        (__attribute__((address_space(3))) unsigned int*)l, 16, 0, 0);
}

// ---------------- k0: W1 -> W1T bf16 [128][256]; W2 -> W2T bf16 [128][128]
__global__ void k0_transpose(const float* __restrict__ W1, const float* __restrict__ W2,
                             unsigned short* __restrict__ W1T, unsigned short* __restrict__ W2T)
{
    const int tid  = blockIdx.x * blockDim.x + threadIdx.x;
    const int nthr = gridDim.x * blockDim.x;
    for (int i = tid; i < FEAT * EMB; i += nthr) {
        const int r = i >> 7, c = i & 127;
        W1T[c * FEAT + r] = bf16_rne(W1[i]);
    }
    for (int i = tid; i < EMB * EMB; i += nthr) {
        const int r = i >> 7, c = i & 127;
        W2T[c * EMB + r] = bf16_rne(W2[i]);
    }
}

// ---------------- k1: h = x@W1 + b1 ; emit h bf16, hT bf16, UT[q][i] (fused)
__global__ __launch_bounds__(256) void k1_proj(
    const float* __restrict__ x, const unsigned short* __restrict__ W1T,
    const float* __restrict__ b1,
    unsigned short* __restrict__ h, unsigned short* __restrict__ hT,
    float* __restrict__ UT)
{
    __shared__ __align__(16) unsigned char W1s[65536];   // 128 rows x 512 B, blk b' = b ^ (row&15)
    __shared__ unsigned short ldsT[128 * 68];
    const int lane = threadIdx.x & 63;
    const int wave = threadIdx.x >> 6;
    const int quad = lane >> 4;
    const int l15  = lane & 15;
    const int arow = blockIdx.x * 64 + wave * 16 + l15;

    float4 xv[16];
    #pragma unroll
    for (int ks = 0; ks < 8; ++ks) {
        const float* xp = x + (size_t)arow * FEAT + ks * 32 + quad * 8;
        xv[2 * ks]     = *(const float4*)xp;
        xv[2 * ks + 1] = *(const float4*)(xp + 4);
    }
    #pragma unroll
    for (int c = 0; c < 16; ++c) {
        const int chunk = wave * 16 + c;
        const int row = chunk * 2 + (lane >> 5);
        const int b = (lane & 31) ^ (row & 15);
        async_cp16(W1T + (size_t)row * FEAT + b * 8, W1s + chunk * 1024);
    }
    bf16x8 afr[8];
    #pragma unroll
    for (int ks = 0; ks < 8; ++ks) {
        const float4 xa = xv[2 * ks], xb = xv[2 * ks + 1];
        s16x8 at;
        at[0] = (short)bf16_rne(xa.x); at[1] = (short)bf16_rne(xa.y);
        at[2] = (short)bf16_rne(xa.z); at[3] = (short)bf16_rne(xa.w);
        at[4] = (short)bf16_rne(xb.x); at[5] = (short)bf16_rne(xb.y);
        at[6] = (short)bf16_rne(xb.z); at[7] = (short)bf16_rne(xb.w);
        afr[ks] = __builtin_bit_cast(bf16x8, at);
    }
    __syncthreads();   // W1s staged (vmcnt drain)

    const f32x4 zero4 = {0.f, 0.f, 0.f, 0.f};
    f32x4 acc[8];
    #pragma unroll
    for (int n0 = 0; n0 < 8; ++n0) acc[n0] = zero4;
    #pragma unroll
    for (int ks = 0; ks < 8; ++ks)
        #pragma unroll
        for (int n0 = 0; n0 < 8; ++n0) {
            const int n = n0 * 16 + l15;
            const int b = (ks * 4 + quad) ^ (n & 15);
            const bf16x8 bfr = *(const bf16x8*)(W1s + n * 512 + b * 16);
            acc[n0] = __builtin_amdgcn_mfma_f32_16x16x32_bf16(afr[ks], bfr, acc[n0], 0, 0, 0);
        }

    const int rbase = blockIdx.x * 64 + wave * 16 + quad * 4;
    float dpart[4] = {0.f, 0.f, 0.f, 0.f};
    #pragma unroll
    for (int n0 = 0; n0 < 8; ++n0) {
        const int col = n0 * 16 + l15;
        const float bias = b1[col];
        unsigned short hb[4];
        #pragma unroll
        for (int r = 0; r < 4; ++r) {
            const float hv = acc[n0][r] + bias;
            const unsigned short q = bf16_rne(hv);
            hb[r] = q;
            const float bb = bf16_to_f32(q);
            dpart[r] += bb * bb;
            h[(size_t)(rbase + r) * EMB + col] = q;
        }
        ushort4 pk = make_ushort4(hb[0], hb[1], hb[2], hb[3]);
        *(ushort4*)&ldsT[col * 68 + wave * 16 + quad * 4] = pk;
    }
    const float tql = __expf(0.9f * (float)l15 - 10.8f);   // lane's quadrature node
    #pragma unroll
    for (int r = 0; r < 4; ++r) {
        float v = dpart[r];
        v += __shfl_xor(v, 1);
        v += __shfl_xor(v, 2);
        v += __shfl_xor(v, 4);
        v += __shfl_xor(v, 8);
        if (l15 < 10)       UT[(size_t)l15 * N_TOK + rbase + r] = __expf(-tql * v);
        else if (l15 == 10) UT[(size_t)10  * N_TOK + rbase + r] = 1.0f;
    }
    __syncthreads();
    const int rbase0 = blockIdx.x * 64;
    #pragma unroll
    for (int i = 0; i < 4; ++i) {
        const int slot = i * 256 + threadIdx.x;
        const int c    = slot >> 3;
        const int seg  = slot & 7;
        const ushort4 a0 = *(const ushort4*)&ldsT[c * 68 + seg * 8];
        const ushort4 a1 = *(const ushort4*)&ldsT[c * 68 + seg * 8 + 4];
        ushort4 o[2] = {a0, a1};
        *(uint4*)&hT[(size_t)c * N_TOK + rbase0 + seg * 8] = *(const uint4*)o;
    }
}

// ---------------- k2a: Gram partials, SYMMETRY-SPLIT (R22). G_q = h^T diag(u^q) h is
// symmetric -> skip the (rows 64-127 x cols 0-63) super-tile. 3 block types per (q,kc):
//   t=0 diag0: rows 0-63  x cols 0-63   (stages rows 0-63 only)
//   t=1 upper: rows 0-63  x cols 64-127 (stages all 128 rows)
//   t=2 diag1: rows 64-127 x cols 64-127 (stages rows 64-127 only)
// Grid = 11*16*3 = 528 ~ 2.06x256 (near-perfect 2-blocks/CU balance vs R21's 1.375x).
// 25% fewer MFMA + A-pack VALU; aggregate staging unchanged; Gp 11 -> 8.25 MB.
// Each block: 4 waves, wave = A-row 16-group; acc[4] (16 rows x 64 cols). k2b mirrors
// the skipped quadrant (trunc-side differs by ~2^-9 rel -- same class as pack noise).
#define K2A_STAGE(sub_, dst_) do {                                              \
    const int kwin_ = kc * 1024 + (sub_) * 128;                                 \
    for (int c = 0; c < nchw; ++c) {                                            \
        const int chunk = wave * nchw + c;                                      \
        const int lrow = chunk * 4 + (lane >> 4);                               \
        const int b = (lane & 15) ^ (lrow & 15);                                \
        async_cp16(hT + (size_t)(stagebase + lrow) * N_TOK + kwin_ + b * 8,     \
                   (dst_) + chunk * 1024);                                      \
    } } while (0)

__global__ __launch_bounds__(256, 2) void k2a_gram(
    const unsigned short* __restrict__ hT, const float* __restrict__ UT,
    float* __restrict__ Gp)
{
    __shared__ __align__(16) unsigned char Rb[2][32768];   // dbuf: up to 128 rows x 256 B
    const int lane = threadIdx.x & 63;
    const int wave = threadIdx.x >> 6;    // 0..3 = A-row 16-group
    const int quad = lane >> 4;
    const int l15  = lane & 15;
    const int bid  = blockIdx.x;
    const int q    = bid / (KC * 3);
    const int rem  = bid - q * (KC * 3);
    const int kc   = rem / 3;
    const int t    = rem - kc * 3;        // 0,1,2 per comment above
    const int stagebase = (t == 2) ? 64 : 0;
    const int nchw = (t == 1) ? 8 : 4;    // staged chunks per wave (4 rows each)
    const int boff = (t == 1) ? 64 : 0;   // B rows local offset within staged window

    const f32x4 zero4 = {0.f, 0.f, 0.f, 0.f};
    f32x4 acc[4];
    #pragma unroll
    for (int nt = 0; nt < 4; ++nt) acc[nt] = zero4;

    K2A_STAGE(0, Rb[0]);
    __syncthreads();   // buf0 staged

    #pragma unroll 1
    for (int sub = 0; sub < 8; ++sub) {
        if (sub < 7) K2A_STAGE(sub + 1, Rb[(sub + 1) & 1]);   // prefetch next window
        const unsigned char* rb = Rb[sub & 1];
        const int kwin = kc * 1024 + sub * 128;

        #pragma unroll
        for (int ks = 0; ks < 4; ++ks) {
            const int kb = kwin + ks * 32 + quad * 8;
            const float4 ua = *(const float4*)(UT + (size_t)q * N_TOK + kb);
            const float4 ub = *(const float4*)(UT + (size_t)q * N_TOK + kb + 4);
            const float uv[8] = {ua.x, ua.y, ua.z, ua.w, ub.x, ub.y, ub.z, ub.w};
            // A frag: local row = wave*16 + l15 (A rows always start at staged base)
            const int re = wave * 16 + l15;
            const int ba = (ks * 4 + quad) ^ (re & 15);
            const s16x8 raw = *(const s16x8*)(rb + re * 256 + ba * 16);
            u32x4 ww;
            #pragma unroll
            for (int w = 0; w < 4; ++w) {
                const float fa = bf16_to_f32((unsigned short)raw[2 * w])     * uv[2 * w];
                const float fb = bf16_to_f32((unsigned short)raw[2 * w + 1]) * uv[2 * w + 1];
                ww[w] = pack_trunc(fa, fb);
            }
            const bf16x8 au = __builtin_bit_cast(bf16x8, ww);
            #pragma unroll
            for (int nt = 0; nt < 4; ++nt) {
                const int rf = boff + nt * 16 + l15;
                const int bb = (ks * 4 + quad) ^ (rf & 15);
                const bf16x8 bfr = *(const bf16x8*)(rb + rf * 256 + bb * 16);
                acc[nt] = __builtin_amdgcn_mfma_f32_16x16x32_bf16(au, bfr, acc[nt], 0, 0, 0);
            }
        }
        if (sub < 7) __syncthreads();   // next buf staged + this buf's reads done
    }

    // slab = ((q*KC+kc)*3 + t), 64x64 f32
    float* gp = Gp + (size_t)((q * KC + kc) * 3 + t) * 4096;
    #pragma unroll
    for (int nt = 0; nt < 4; ++nt)
        #pragma unroll
        for (int r = 0; r < 4; ++r)
            gp[(wave * 16 + quad * 4 + r) * 64 + nt * 16 + l15] = acc[nt][r];
}

// ---------------- k2b: fused reduce + GWT. Phase 1 (R22): gather the 16x128 G-slice
// from the 3 symmetric slabs per kc -- rows<64: {diag0 | upper}; rows>=64: {mirrored
// upper (transposed, 8 stride-64 scalar reads/lane) | diag1}. Then reduce over KC and
// pack to swizzled bf16 LDS. Phase 2 unchanged: GWT = (2 w_q) * W2T @ Gs^T.
__global__ __launch_bounds__(256) void k2b_gwt(
    const float* __restrict__ Gp, const unsigned short* __restrict__ W2T,
    unsigned short* __restrict__ GWT)
{
    __shared__ __align__(16) unsigned char Gs[16 * 256];   // 16 rows x 256 B, blk b' = b ^ row
    const int q  = blockIdx.x >> 3;     // 0..10
    const int fs = blockIdx.x & 7;      // f-subtile (16 rows)
    const int tid = threadIdx.x;

    // phase 1: reduce KC partials for rows [fs*16, fs*16+16) x 128 cols
    {
        const int fg  = tid >> 4;       // local row 0..15
        const int blk = tid & 15;       // 16B block: 8 consecutive f32 k-elems
        const int fgG = fs * 16 + fg;   // global f-row (band is block-uniform in 64-halves)
        const float* base0 = Gp + (size_t)q * (KC * 3) * 4096;
        float s[8] = {0.f, 0.f, 0.f, 0.f, 0.f, 0.f, 0.f, 0.f};
        if (fs < 4) {
            // rows 0-63: direct from diag0 (k<64) or upper (k>=64)
            const int t   = (blk < 8) ? 0 : 1;
            const int off = fgG * 64 + (blk & 7) * 8;
            #pragma unroll
            for (int kc = 0; kc < KC; ++kc) {
                const float* p = base0 + (size_t)(kc * 3 + t) * 4096 + off;
                const float4 a = *(const float4*)p;
                const float4 b = *(const float4*)(p + 4);
                s[0] += a.x; s[1] += a.y; s[2] += a.z; s[3] += a.w;
                s[4] += b.x; s[5] += b.y; s[6] += b.z; s[7] += b.w;
            }
        } else if (blk >= 8) {
            // rows 64-127, k>=64: direct from diag1
            const int off = (fgG - 64) * 64 + (blk - 8) * 8;
            #pragma unroll
            for (int kc = 0; kc < KC; ++kc) {
                const float* p = base0 + (size_t)(kc * 3 + 2) * 4096 + off;
                const float4 a = *(const float4*)p;
                const float4 b = *(const float4*)(p + 4);
                s[0] += a.x; s[1] += a.y; s[2] += a.z; s[3] += a.w;
                s[4] += b.x; s[5] += b.y; s[6] += b.z; s[7] += b.w;
            }
        } else {
            // rows 64-127, k<64: mirror -- G[f][k] = upper[k][f-64]
            const int col = fgG - 64;
            #pragma unroll
            for (int kc = 0; kc < KC; ++kc) {
                const float* p = base0 + (size_t)(kc * 3 + 1) * 4096 + blk * 8 * 64 + col;
                #pragma unroll
                for (int j = 0; j < 8; ++j) s[j] += p[j * 64];
            }
        }
        u32x4 w;
        w[0] = pack_rne(s[0], s[1]);
        w[1] = pack_rne(s[2], s[3]);
        w[2] = pack_rne(s[4], s[5]);
        w[3] = pack_rne(s[6], s[7]);
        *(u32x4*)(Gs + fg * 256 + ((blk ^ fg) << 4)) = w;
    }
    __syncthreads();

    // phase 2: GWT = scale * W2T @ Gs^T (MFMA, B-frag rows = G rows fg)
    const int lane = tid & 63;
    const int wave = tid >> 6;
    const int quad = lane >> 4;
    const int l15  = lane & 15;
    const float scale = (q == 10) ? 2.0f * __expf(-10.8f)
                                  : 1.8f * __expf(0.9f * (float)q - 10.8f);  // 2*w_q

    const f32x4 zero4 = {0.f, 0.f, 0.f, 0.f};
    f32x4 acc[2];
    acc[0] = zero4; acc[1] = zero4;
    #pragma unroll
    for (int ks = 0; ks < 4; ++ks) {
        const int b = (ks * 4 + quad) ^ l15;
        const bf16x8 bfr = *(const bf16x8*)(Gs + l15 * 256 + b * 16);
        #pragma unroll
        for (int mt = 0; mt < 2; ++mt) {
            const int o = wave * 32 + mt * 16 + l15;
            const bf16x8 afr = *(const bf16x8*)(W2T + (size_t)o * EMB + ks * 32 + quad * 8);
            acc[mt] = __builtin_amdgcn_mfma_f32_16x16x32_bf16(afr, bfr, acc[mt], 0, 0, 0);
        }
    }
    #pragma unroll
    for (int mt = 0; mt < 2; ++mt)
        #pragma unroll
        for (int r = 0; r < 4; ++r)
            GWT[(size_t)q * (EMB * EMB) + (size_t)(wave * 32 + mt * 16 + quad * 4 + r) * EMB + fs * 16 + l15]
                = bf16_rne(acc[mt][r] * scale);
}

// ---------------- k2c: out[i][o] = relu(b2[o] + sum_q u_i^q * (h_i . GWT_q[o][:]))
// R20: LDS-staged dbuf template, block = 32 i x 64 o, 4 blocks/CU so the NQ serial
// barrier-drain phases overlap across co-resident blocks.
__global__ __launch_bounds__(256, 4) void k2c_apply(
    const unsigned short* __restrict__ h, const unsigned short* __restrict__ GWT,
    const float* __restrict__ UT, const float* __restrict__ b2,
    float* __restrict__ out)
{
    __shared__ __align__(16) unsigned char Gs[2][16384];   // dbuf: 64 o-rows x 256 B
    const int lane = threadIdx.x & 63;
    const int wave = threadIdx.x >> 6;    // 0..3
    const int quad = lane >> 4;
    const int l15  = lane & 15;
    const int ih   = wave & 1;            // i 16-half within the 32-row block
    const int oh   = wave >> 1;           // o 32-half within the 64-col slice
    const int i0   = (blockIdx.x >> 1) * 32;
    const int o0   = (blockIdx.x & 1) * 64;
    const int irow = i0 + ih * 16 + l15;

    bf16x8 araw[4];
    #pragma unroll
    for (int ks = 0; ks < 4; ++ks)
        araw[ks] = *(const bf16x8*)(h + (size_t)irow * EMB + ks * 32 + quad * 8);

    const f32x4 zero4 = {0.f, 0.f, 0.f, 0.f};
    f32x4 acc[2];
    acc[0] = zero4; acc[1] = zero4;

    // stage q=0: 16 chunks x 1KB (4 rows x 256B each), 4 chunks/wave
    #pragma unroll
    for (int c = 0; c < 4; ++c) {
        const int chunk = wave * 4 + c;
        const int row = chunk * 4 + quad;          // local o-row 0..63
        const int b = l15 ^ (row & 15);
        async_cp16(GWT + (size_t)(o0 + row) * EMB + b * 8, &Gs[0][chunk * 1024]);
    }
    #pragma unroll 1
    for (int q = 0; q < NQ; ++q) {
        __syncthreads();   // stage(q) complete (vmcnt drain) + prev compute's reads done
        if (q + 1 < NQ) {
            const unsigned short* src = GWT + (size_t)(q + 1) * (EMB * EMB);
            unsigned char* dst = Gs[(q + 1) & 1];
            #pragma unroll
            for (int c = 0; c < 4; ++c) {
                const int chunk = wave * 4 + c;
                const int row = chunk * 4 + quad;
                const int b = l15 ^ (row & 15);
                async_cp16(src + (size_t)(o0 + row) * EMB + b * 8, dst + chunk * 1024);
            }
        }
        const float4 uq = *(const float4*)(UT + (size_t)q * N_TOK + i0 + ih * 16 + quad * 4);
        const unsigned char* gb = Gs[q & 1];
        #pragma unroll
        for (int nt = 0; nt < 2; ++nt) {
            const int ol = oh * 32 + nt * 16 + l15;   // local o-row 0..63
            f32x4 t = zero4;
            #pragma unroll
            for (int ks = 0; ks < 4; ++ks) {
                const int b = (ks * 4 + quad) ^ (ol & 15);
                const bf16x8 bfr = *(const bf16x8*)(gb + ol * 256 + b * 16);
                t = __builtin_amdgcn_mfma_f32_16x16x32_bf16(araw[ks], bfr, t, 0, 0, 0);
            }
            acc[nt][0] += uq.x * t[0];
            acc[nt][1] += uq.y * t[1];
            acc[nt][2] += uq.z * t[2];
            acc[nt][3] += uq.w * t[3];
        }
    }

    #pragma unroll
    for (int nt = 0; nt < 2; ++nt) {
        const int o = o0 + oh * 32 + nt * 16 + l15;
        const float bias = b2[o];
        #pragma unroll
        for (int r = 0; r < 4; ++r) {
            const float v = acc[nt][r] + bias;
            out[(size_t)(i0 + ih * 16 + quad * 4 + r) * EMB + o] = v > 0.f ? v : 0.f;
        }
    }
}

extern "C" void kernel_launch(void* const* d_in, const int* in_sizes, int n_in,
                              void* d_out, int out_size, void* d_ws, size_t ws_size,
                              hipStream_t stream) {
    const float* x  = (const float*)d_in[0];
    const float* W1 = (const float*)d_in[1];
    const float* b1 = (const float*)d_in[2];
    const float* W2 = (const float*)d_in[3];
    const float* b2 = (const float*)d_in[4];
    float* out = (float*)d_out;

    char* ws = (char*)d_ws;
    // ws (bytes): h 4MB | hT 4MB | W1T 64KB | W2T 32KB | UT 832KB
    // | Gp 11x16x3x16KB (8.25MB) | (gap) | GWT 352KB
    unsigned short* h   = (unsigned short*)(ws);
    unsigned short* hT  = (unsigned short*)(ws + 4194304);
    unsigned short* W1T = (unsigned short*)(ws + 8388608);
    unsigned short* W2T = (unsigned short*)(ws + 8454144);
    float*          UT  = (float*)        (ws + 8486912);
    float*          Gp  = (float*)        (ws + 9338880);
    unsigned short* GWT = (unsigned short*)(ws + 23920640);

    k0_transpose<<<dim3(64),          dim3(256), 0, stream>>>(W1, W2, W1T, W2T);
    k1_proj     <<<dim3(256),         dim3(256), 0, stream>>>(x, W1T, b1, h, hT, UT);
    k2a_gram    <<<dim3(NQ * KC * 3), dim3(256), 0, stream>>>(hT, UT, Gp);
    k2b_gwt     <<<dim3(NQ * 8),      dim3(256), 0, stream>>>(Gp, W2T, GWT);
    k2c_apply   <<<dim3(1024),        dim3(256), 0, stream>>>(h, GWT, UT, b2, out);
}

// Round 11
// 117.459 us; speedup vs baseline: 1.1036x; 1.1036x over previous
//
#include <hip/hip_runtime.h>
#include <stdint.h>

// Problem constants
#define N_TOK 16384
#define FEAT  256
#define EMB   128
#define NQ    11   // 10 sinc-quadrature nodes (t_q=e^{-10.8+0.9q}, q=0..9) + 1 analytic t=0 tail
#define KC    16   // K-chunks in k2a: 1024 tokens each.

typedef float  f32x4  __attribute__((ext_vector_type(4)));
typedef __bf16 bf16x8 __attribute__((ext_vector_type(8)));
typedef short  s16x8  __attribute__((ext_vector_type(8)));
typedef unsigned int u32x4 __attribute__((ext_vector_type(4)));

__device__ __forceinline__ unsigned short bf16_rne(float f) {
    union { float f; unsigned u; } v; v.f = f;
    unsigned u = v.u;
    return (unsigned short)((u + 0x7FFFu + ((u >> 16) & 1u)) >> 16);
}
__device__ __forceinline__ float bf16_to_f32(unsigned short s) {
    union { unsigned u; float f; } v; v.u = ((unsigned)s) << 16; return v.f;
}
// pack two f32 -> (bf16(a) | bf16(b)<<16) by truncation; bias ~2^-9 rel
__device__ __forceinline__ unsigned pack_trunc(float a, float b) {
    union { float f; unsigned u; } ua, ub; ua.f = a; ub.f = b;
    return (ub.u & 0xFFFF0000u) | (ua.u >> 16);
}
// pack two f32 -> bf16 pair with RNE (used where values feed many downstream MFMAs)
__device__ __forceinline__ unsigned pack_rne(float a, float b) {
    return (unsigned)bf16_rne(a) | ((unsigned)bf16_rne(b) << 16);
}
__device__ __forceinline__ void async_cp16(const void* g, void* l) {
    __builtin_amdgcn_global_load_lds(
        (const __attribute__((address_space(1))) unsigned int*)g,
        (__attribute__((address_space(3))) unsigned int*)l, 16, 0, 0);
}

// ---------------- k0: W1 -> W1T bf16 [128][256]; W2 -> W2T bf16 [128][128]
__global__ void k0_transpose(const float* __restrict__ W1, const float* __restrict__ W2,
                             unsigned short* __restrict__ W1T, unsigned short* __restrict__ W2T)
{
    const int tid  = blockIdx.x * blockDim.x + threadIdx.x;
    const int nthr = gridDim.x * blockDim.x;
    for (int i = tid; i < FEAT * EMB; i += nthr) {
        const int r = i >> 7, c = i & 127;
        W1T[c * FEAT + r] = bf16_rne(W1[i]);
    }
    for (int i = tid; i < EMB * EMB; i += nthr) {
        const int r = i >> 7, c = i & 127;
        W2T[c * EMB + r] = bf16_rne(W2[i]);
    }
}

// ---------------- k1: h = x@W1 + b1 ; emit h bf16, hT bf16, UT[q][i] (fused)
__global__ __launch_bounds__(256) void k1_proj(
    const float* __restrict__ x, const unsigned short* __restrict__ W1T,
    const float* __restrict__ b1,
    unsigned short* __restrict__ h, unsigned short* __restrict__ hT,
    float* __restrict__ UT)
{
    __shared__ __align__(16) unsigned char W1s[65536];   // 128 rows x 512 B, blk b' = b ^ (row&15)
    __shared__ unsigned short ldsT[128 * 68];
    const int lane = threadIdx.x & 63;
    const int wave = threadIdx.x >> 6;
    const int quad = lane >> 4;
    const int l15  = lane & 15;
    const int arow = blockIdx.x * 64 + wave * 16 + l15;

    float4 xv[16];
    #pragma unroll
    for (int ks = 0; ks < 8; ++ks) {
        const float* xp = x + (size_t)arow * FEAT + ks * 32 + quad * 8;
        xv[2 * ks]     = *(const float4*)xp;
        xv[2 * ks + 1] = *(const float4*)(xp + 4);
    }
    #pragma unroll
    for (int c = 0; c < 16; ++c) {
        const int chunk = wave * 16 + c;
        const int row = chunk * 2 + (lane >> 5);
        const int b = (lane & 31) ^ (row & 15);
        async_cp16(W1T + (size_t)row * FEAT + b * 8, W1s + chunk * 1024);
    }
    bf16x8 afr[8];
    #pragma unroll
    for (int ks = 0; ks < 8; ++ks) {
        const float4 xa = xv[2 * ks], xb = xv[2 * ks + 1];
        s16x8 at;
        at[0] = (short)bf16_rne(xa.x); at[1] = (short)bf16_rne(xa.y);
        at[2] = (short)bf16_rne(xa.z); at[3] = (short)bf16_rne(xa.w);
        at[4] = (short)bf16_rne(xb.x); at[5] = (short)bf16_rne(xb.y);
        at[6] = (short)bf16_rne(xb.z); at[7] = (short)bf16_rne(xb.w);
        afr[ks] = __builtin_bit_cast(bf16x8, at);
    }
    __syncthreads();   // W1s staged (vmcnt drain)

    const f32x4 zero4 = {0.f, 0.f, 0.f, 0.f};
    f32x4 acc[8];
    #pragma unroll
    for (int n0 = 0; n0 < 8; ++n0) acc[n0] = zero4;
    #pragma unroll
    for (int ks = 0; ks < 8; ++ks)
        #pragma unroll
        for (int n0 = 0; n0 < 8; ++n0) {
            const int n = n0 * 16 + l15;
            const int b = (ks * 4 + quad) ^ (n & 15);
            const bf16x8 bfr = *(const bf16x8*)(W1s + n * 512 + b * 16);
            acc[n0] = __builtin_amdgcn_mfma_f32_16x16x32_bf16(afr[ks], bfr, acc[n0], 0, 0, 0);
        }

    const int rbase = blockIdx.x * 64 + wave * 16 + quad * 4;
    float dpart[4] = {0.f, 0.f, 0.f, 0.f};
    #pragma unroll
    for (int n0 = 0; n0 < 8; ++n0) {
        const int col = n0 * 16 + l15;
        const float bias = b1[col];
        unsigned short hb[4];
        #pragma unroll
        for (int r = 0; r < 4; ++r) {
            const float hv = acc[n0][r] + bias;
            const unsigned short q = bf16_rne(hv);
            hb[r] = q;
            const float bb = bf16_to_f32(q);
            dpart[r] += bb * bb;
            h[(size_t)(rbase + r) * EMB + col] = q;
        }
        ushort4 pk = make_ushort4(hb[0], hb[1], hb[2], hb[3]);
        *(ushort4*)&ldsT[col * 68 + wave * 16 + quad * 4] = pk;
    }
    const float tql = __expf(0.9f * (float)l15 - 10.8f);   // lane's quadrature node
    #pragma unroll
    for (int r = 0; r < 4; ++r) {
        float v = dpart[r];
        v += __shfl_xor(v, 1);
        v += __shfl_xor(v, 2);
        v += __shfl_xor(v, 4);
        v += __shfl_xor(v, 8);
        if (l15 < 10)       UT[(size_t)l15 * N_TOK + rbase + r] = __expf(-tql * v);
        else if (l15 == 10) UT[(size_t)10  * N_TOK + rbase + r] = 1.0f;
    }
    __syncthreads();
    const int rbase0 = blockIdx.x * 64;
    #pragma unroll
    for (int i = 0; i < 4; ++i) {
        const int slot = i * 256 + threadIdx.x;
        const int c    = slot >> 3;
        const int seg  = slot & 7;
        const ushort4 a0 = *(const ushort4*)&ldsT[c * 68 + seg * 8];
        const ushort4 a1 = *(const ushort4*)&ldsT[c * 68 + seg * 8 + 4];
        ushort4 o[2] = {a0, a1};
        *(uint4*)&hT[(size_t)c * N_TOK + rbase0 + seg * 8] = *(const uint4*)o;
    }
}

// ---------------- k2a: Gram partials G_q = h^T diag(u^q) h, K split 16 x 1024.
// R23: REVERT to R21 (symmetry split R22 regressed: thinner MFMA phases exposed the
// barrier drains + k2b mirror gather cost; phase structure dominates, not FLOPs).
// R21 structure: 256-thr blocks (4 waves, wave=E row-32-group; F o-half from blockIdx),
// grid NQ*KC*2 = 352, LDS dbuf 2x32KB -> 2 blocks/CU; barrier drains overlap across the
// two co-resident blocks. One change vs R21: Gp stored bf16 (halves Gp round-trip).
#define K2A_STAGE(sub_, dst_) do {                                              \
    const int kwin_ = kc * 1024 + (sub_) * 128;                                 \
    _Pragma("unroll")                                                           \
    for (int c = 0; c < 8; ++c) {                                               \
        const int chunk = wave * 8 + c;                                         \
        const int row = chunk * 4 + (lane >> 4);                                \
        const int b = (lane & 15) ^ (row & 15);                                 \
        async_cp16(hT + (size_t)row * N_TOK + kwin_ + b * 8, (dst_) + chunk * 1024); \
    } } while (0)

__global__ __launch_bounds__(256, 2) void k2a_gram(
    const unsigned short* __restrict__ hT, const float* __restrict__ UT,
    unsigned short* __restrict__ Gp)
{
    __shared__ __align__(16) unsigned char Rb[2][32768];   // dbuf: 128 rows x 256 B each
    const int lane = threadIdx.x & 63;
    const int wave = threadIdx.x >> 6;    // 0..3 = E row-32-group
    const int quad = lane >> 4;
    const int l15  = lane & 15;
    const int q  = blockIdx.x >> 5;       // 0..10
    const int kc = (blockIdx.x >> 1) & 15;
    const int F  = blockIdx.x & 1;        // o-half (64 cols)
    const int E  = wave;

    const f32x4 zero4 = {0.f, 0.f, 0.f, 0.f};
    f32x4 acc[2][4];
    #pragma unroll
    for (int mt = 0; mt < 2; ++mt)
        #pragma unroll
        for (int nt = 0; nt < 4; ++nt) acc[mt][nt] = zero4;

    K2A_STAGE(0, Rb[0]);
    __syncthreads();   // buf0 staged

    #pragma unroll 1
    for (int sub = 0; sub < 8; ++sub) {
        if (sub < 7) K2A_STAGE(sub + 1, Rb[(sub + 1) & 1]);   // prefetch next window
        const unsigned char* rb = Rb[sub & 1];
        const int kwin = kc * 1024 + sub * 128;

        #pragma unroll
        for (int ks = 0; ks < 4; ++ks) {
            const int kb = kwin + ks * 32 + quad * 8;
            const float4 ua = *(const float4*)(UT + (size_t)q * N_TOK + kb);
            const float4 ub = *(const float4*)(UT + (size_t)q * N_TOK + kb + 4);
            const float uv[8] = {ua.x, ua.y, ua.z, ua.w, ub.x, ub.y, ub.z, ub.w};
            bf16x8 au[2];
            #pragma unroll
            for (int mt = 0; mt < 2; ++mt) {
                const int re = E * 32 + mt * 16 + l15;
                const int b = (ks * 4 + quad) ^ (re & 15);
                const s16x8 raw = *(const s16x8*)(rb + re * 256 + b * 16);
                u32x4 ww;
                #pragma unroll
                for (int w = 0; w < 4; ++w) {
                    const float fa = bf16_to_f32((unsigned short)raw[2 * w])     * uv[2 * w];
                    const float fb = bf16_to_f32((unsigned short)raw[2 * w + 1]) * uv[2 * w + 1];
                    ww[w] = pack_trunc(fa, fb);
                }
                au[mt] = __builtin_bit_cast(bf16x8, ww);
            }
            #pragma unroll
            for (int nt = 0; nt < 4; ++nt) {
                const int rf = F * 64 + nt * 16 + l15;
                const int b = (ks * 4 + quad) ^ (rf & 15);
                const bf16x8 bfr = *(const bf16x8*)(rb + rf * 256 + b * 16);
                #pragma unroll
                for (int mt = 0; mt < 2; ++mt)
                    acc[mt][nt] = __builtin_amdgcn_mfma_f32_16x16x32_bf16(au[mt], bfr, acc[mt][nt], 0, 0, 0);
            }
        }
        if (sub < 7) __syncthreads();   // next buf staged + this buf's reads done
    }

    // Gp bf16 (R23): partial quantization 2^-8 RNE before the 16-way sum -- same noise
    // class as k2b's existing bf16 pack of G. Halves Gp write+read bytes.
    unsigned short* gp = Gp + (size_t)(q * KC + kc) * (EMB * EMB);
    #pragma unroll
    for (int mt = 0; mt < 2; ++mt)
        #pragma unroll
        for (int nt = 0; nt < 4; ++nt)
            #pragma unroll
            for (int r = 0; r < 4; ++r)
                gp[(size_t)(E * 32 + mt * 16 + quad * 4 + r) * EMB + F * 64 + nt * 16 + l15]
                    = bf16_rne(acc[mt][nt][r]);
}

// ---------------- k2b: fused reduce + GWT. Phase 1: block reduces its 16x128 slice
// over the 16 bf16 Gp partials (16B ushort8 loads, cvt+sum in f32) into a swizzled
// bf16 LDS tile. Phase 2: GWT = (2 w_q) * W2T @ Gs^T via MFMA.
__global__ __launch_bounds__(256) void k2b_gwt(
    const unsigned short* __restrict__ Gp, const unsigned short* __restrict__ W2T,
    unsigned short* __restrict__ GWT)
{
    __shared__ __align__(16) unsigned char Gs[16 * 256];   // 16 rows x 256 B, blk b' = b ^ row
    const int q  = blockIdx.x >> 3;     // 0..10
    const int fs = blockIdx.x & 7;      // f-subtile (16 rows)
    const int tid = threadIdx.x;

    // phase 1: reduce KC partials for rows [fs*16, fs*16+16) x 128 cols
    {
        const int fg  = tid >> 4;       // local row 0..15
        const int blk = tid & 15;       // 16B block: 8 consecutive bf16 k-elems
        const unsigned short* src = Gp + (size_t)q * KC * (EMB * EMB)
                                       + (size_t)(fs * 16 + fg) * EMB + blk * 8;
        float s[8] = {0.f, 0.f, 0.f, 0.f, 0.f, 0.f, 0.f, 0.f};
        #pragma unroll
        for (int kc = 0; kc < KC; ++kc) {
            const s16x8 raw = *(const s16x8*)(src + (size_t)kc * (EMB * EMB));
            #pragma unroll
            for (int j = 0; j < 8; ++j)
                s[j] += bf16_to_f32((unsigned short)raw[j]);
        }
        u32x4 w;
        w[0] = pack_rne(s[0], s[1]);
        w[1] = pack_rne(s[2], s[3]);
        w[2] = pack_rne(s[4], s[5]);
        w[3] = pack_rne(s[6], s[7]);
        *(u32x4*)(Gs + fg * 256 + ((blk ^ fg) << 4)) = w;
    }
    __syncthreads();

    // phase 2: GWT = scale * W2T @ Gs^T (MFMA, B-frag rows = G rows fg)
    const int lane = tid & 63;
    const int wave = tid >> 6;
    const int quad = lane >> 4;
    const int l15  = lane & 15;
    const float scale = (q == 10) ? 2.0f * __expf(-10.8f)
                                  : 1.8f * __expf(0.9f * (float)q - 10.8f);  // 2*w_q

    const f32x4 zero4 = {0.f, 0.f, 0.f, 0.f};
    f32x4 acc[2];
    acc[0] = zero4; acc[1] = zero4;
    #pragma unroll
    for (int ks = 0; ks < 4; ++ks) {
        const int b = (ks * 4 + quad) ^ l15;
        const bf16x8 bfr = *(const bf16x8*)(Gs + l15 * 256 + b * 16);
        #pragma unroll
        for (int mt = 0; mt < 2; ++mt) {
            const int o = wave * 32 + mt * 16 + l15;
            const bf16x8 afr = *(const bf16x8*)(W2T + (size_t)o * EMB + ks * 32 + quad * 8);
            acc[mt] = __builtin_amdgcn_mfma_f32_16x16x32_bf16(afr, bfr, acc[mt], 0, 0, 0);
        }
    }
    #pragma unroll
    for (int mt = 0; mt < 2; ++mt)
        #pragma unroll
        for (int r = 0; r < 4; ++r)
            GWT[(size_t)q * (EMB * EMB) + (size_t)(wave * 32 + mt * 16 + quad * 4 + r) * EMB + fs * 16 + l15]
                = bf16_rne(acc[mt][r] * scale);
}

// ---------------- k2c: out[i][o] = relu(b2[o] + sum_q u_i^q * (h_i . GWT_q[o][:]))
// R20: LDS-staged dbuf template, block = 32 i x 64 o, 4 blocks/CU so the NQ serial
// barrier-drain phases overlap across co-resident blocks.
__global__ __launch_bounds__(256, 4) void k2c_apply(
    const unsigned short* __restrict__ h, const unsigned short* __restrict__ GWT,
    const float* __restrict__ UT, const float* __restrict__ b2,
    float* __restrict__ out)
{
    __shared__ __align__(16) unsigned char Gs[2][16384];   // dbuf: 64 o-rows x 256 B
    const int lane = threadIdx.x & 63;
    const int wave = threadIdx.x >> 6;    // 0..3
    const int quad = lane >> 4;
    const int l15  = lane & 15;
    const int ih   = wave & 1;            // i 16-half within the 32-row block
    const int oh   = wave >> 1;           // o 32-half within the 64-col slice
    const int i0   = (blockIdx.x >> 1) * 32;
    const int o0   = (blockIdx.x & 1) * 64;
    const int irow = i0 + ih * 16 + l15;

    bf16x8 araw[4];
    #pragma unroll
    for (int ks = 0; ks < 4; ++ks)
        araw[ks] = *(const bf16x8*)(h + (size_t)irow * EMB + ks * 32 + quad * 8);

    const f32x4 zero4 = {0.f, 0.f, 0.f, 0.f};
    f32x4 acc[2];
    acc[0] = zero4; acc[1] = zero4;

    // stage q=0: 16 chunks x 1KB (4 rows x 256B each), 4 chunks/wave
    #pragma unroll
    for (int c = 0; c < 4; ++c) {
        const int chunk = wave * 4 + c;
        const int row = chunk * 4 + quad;          // local o-row 0..63
        const int b = l15 ^ (row & 15);
        async_cp16(GWT + (size_t)(o0 + row) * EMB + b * 8, &Gs[0][chunk * 1024]);
    }
    #pragma unroll 1
    for (int q = 0; q < NQ; ++q) {
        __syncthreads();   // stage(q) complete (vmcnt drain) + prev compute's reads done
        if (q + 1 < NQ) {
            const unsigned short* src = GWT + (size_t)(q + 1) * (EMB * EMB);
            unsigned char* dst = Gs[(q + 1) & 1];
            #pragma unroll
            for (int c = 0; c < 4; ++c) {
                const int chunk = wave * 4 + c;
                const int row = chunk * 4 + quad;
                const int b = l15 ^ (row & 15);
                async_cp16(src + (size_t)(o0 + row) * EMB + b * 8, dst + chunk * 1024);
            }
        }
        const float4 uq = *(const float4*)(UT + (size_t)q * N_TOK + i0 + ih * 16 + quad * 4);
        const unsigned char* gb = Gs[q & 1];
        #pragma unroll
        for (int nt = 0; nt < 2; ++nt) {
            const int ol = oh * 32 + nt * 16 + l15;   // local o-row 0..63
            f32x4 t = zero4;
            #pragma unroll
            for (int ks = 0; ks < 4; ++ks) {
                const int b = (ks * 4 + quad) ^ (ol & 15);
                const bf16x8 bfr = *(const bf16x8*)(gb + ol * 256 + b * 16);
                t = __builtin_amdgcn_mfma_f32_16x16x32_bf16(araw[ks], bfr, t, 0, 0, 0);
            }
            acc[nt][0] += uq.x * t[0];
            acc[nt][1] += uq.y * t[1];
            acc[nt][2] += uq.z * t[2];
            acc[nt][3] += uq.w * t[3];
        }
    }

    #pragma unroll
    for (int nt = 0; nt < 2; ++nt) {
        const int o = o0 + oh * 32 + nt * 16 + l15;
        const float bias = b2[o];
        #pragma unroll
        for (int r = 0; r < 4; ++r) {
            const float v = acc[nt][r] + bias;
            out[(size_t)(i0 + ih * 16 + quad * 4 + r) * EMB + o] = v > 0.f ? v : 0.f;
        }
    }
}

extern "C" void kernel_launch(void* const* d_in, const int* in_sizes, int n_in,
                              void* d_out, int out_size, void* d_ws, size_t ws_size,
                              hipStream_t stream) {
    const float* x  = (const float*)d_in[0];
    const float* W1 = (const float*)d_in[1];
    const float* b1 = (const float*)d_in[2];
    const float* W2 = (const float*)d_in[3];
    const float* b2 = (const float*)d_in[4];
    float* out = (float*)d_out;

    char* ws = (char*)d_ws;
    // ws (bytes): h 4MB | hT 4MB | W1T 64KB | W2T 32KB | UT 832KB
    // | Gp bf16 11x16x32KB (5.8MB) | (gap) | GWT 352KB
    unsigned short* h   = (unsigned short*)(ws);
    unsigned short* hT  = (unsigned short*)(ws + 4194304);
    unsigned short* W1T = (unsigned short*)(ws + 8388608);
    unsigned short* W2T = (unsigned short*)(ws + 8454144);
    float*          UT  = (float*)        (ws + 8486912);
    unsigned short* Gp  = (unsigned short*)(ws + 9338880);
    unsigned short* GWT = (unsigned short*)(ws + 23920640);

    k0_transpose<<<dim3(64),          dim3(256), 0, stream>>>(W1, W2, W1T, W2T);
    k1_proj     <<<dim3(256),         dim3(256), 0, stream>>>(x, W1T, b1, h, hT, UT);
    k2a_gram    <<<dim3(NQ * KC * 2), dim3(256), 0, stream>>>(hT, UT, Gp);
    k2b_gwt     <<<dim3(NQ * 8),      dim3(256), 0, stream>>>(Gp, W2T, GWT);
    k2c_apply   <<<dim3(1024),        dim3(256), 0, stream>>>(h, GWT, UT, b2, out);
}

// Round 12
// 109.691 us; speedup vs baseline: 1.1817x; 1.0708x over previous
//
#include <hip/hip_runtime.h>
#include <stdint.h>

// Problem constants
#define N_TOK 16384
#define FEAT  256
#define EMB   128
#define NQ    11   // 10 sinc-quadrature nodes (t_q=e^{-10.8+0.9q}, q=0..9) + 1 analytic t=0 tail
#define KC    16   // K-chunks in k2a: 1024 tokens each.

typedef float  f32x4  __attribute__((ext_vector_type(4)));
typedef __bf16 bf16x8 __attribute__((ext_vector_type(8)));
typedef _Float16 f16x8v __attribute__((ext_vector_type(8)));
typedef short  s16x8  __attribute__((ext_vector_type(8)));
typedef unsigned int u32x4 __attribute__((ext_vector_type(4)));

__device__ __forceinline__ unsigned short bf16_rne(float f) {
    union { float f; unsigned u; } v; v.f = f;
    unsigned u = v.u;
    return (unsigned short)((u + 0x7FFFu + ((u >> 16) & 1u)) >> 16);
}
__device__ __forceinline__ float bf16_to_f32(unsigned short s) {
    union { unsigned u; float f; } v; v.u = ((unsigned)s) << 16; return v.f;
}
__device__ __forceinline__ unsigned short f16_bits(float f) {
    _Float16 h = (_Float16)f;
    return __builtin_bit_cast(unsigned short, h);
}
// pack two f32 -> bf16 pair with RNE (used where values feed many downstream MFMAs)
__device__ __forceinline__ unsigned pack_rne(float a, float b) {
    return (unsigned)bf16_rne(a) | ((unsigned)bf16_rne(b) << 16);
}
__device__ __forceinline__ void async_cp16(const void* g, void* l) {
    __builtin_amdgcn_global_load_lds(
        (const __attribute__((address_space(1))) unsigned int*)g,
        (__attribute__((address_space(3))) unsigned int*)l, 16, 0, 0);
}

// ---------------- k0: W1 -> W1T bf16 [128][256]; W2 -> W2T bf16 [128][128]
__global__ void k0_transpose(const float* __restrict__ W1, const float* __restrict__ W2,
                             unsigned short* __restrict__ W1T, unsigned short* __restrict__ W2T)
{
    const int tid  = blockIdx.x * blockDim.x + threadIdx.x;
    const int nthr = gridDim.x * blockDim.x;
    for (int i = tid; i < FEAT * EMB; i += nthr) {
        const int r = i >> 7, c = i & 127;
        W1T[c * FEAT + r] = bf16_rne(W1[i]);
    }
    for (int i = tid; i < EMB * EMB; i += nthr) {
        const int r = i >> 7, c = i & 127;
        W2T[c * EMB + r] = bf16_rne(W2[i]);
    }
}

// ---------------- k1: h = x@W1 + b1 ; emit h bf16, hT f16 (R24), UT f32 + UTh f16
__global__ __launch_bounds__(256) void k1_proj(
    const float* __restrict__ x, const unsigned short* __restrict__ W1T,
    const float* __restrict__ b1,
    unsigned short* __restrict__ h, unsigned short* __restrict__ hT,
    float* __restrict__ UT, unsigned short* __restrict__ UTh)
{
    __shared__ __align__(16) unsigned char W1s[65536];   // 128 rows x 512 B, blk b' = b ^ (row&15)
    __shared__ unsigned short ldsT[128 * 68];
    const int lane = threadIdx.x & 63;
    const int wave = threadIdx.x >> 6;
    const int quad = lane >> 4;
    const int l15  = lane & 15;
    const int arow = blockIdx.x * 64 + wave * 16 + l15;

    float4 xv[16];
    #pragma unroll
    for (int ks = 0; ks < 8; ++ks) {
        const float* xp = x + (size_t)arow * FEAT + ks * 32 + quad * 8;
        xv[2 * ks]     = *(const float4*)xp;
        xv[2 * ks + 1] = *(const float4*)(xp + 4);
    }
    #pragma unroll
    for (int c = 0; c < 16; ++c) {
        const int chunk = wave * 16 + c;
        const int row = chunk * 2 + (lane >> 5);
        const int b = (lane & 31) ^ (row & 15);
        async_cp16(W1T + (size_t)row * FEAT + b * 8, W1s + chunk * 1024);
    }
    bf16x8 afr[8];
    #pragma unroll
    for (int ks = 0; ks < 8; ++ks) {
        const float4 xa = xv[2 * ks], xb = xv[2 * ks + 1];
        s16x8 at;
        at[0] = (short)bf16_rne(xa.x); at[1] = (short)bf16_rne(xa.y);
        at[2] = (short)bf16_rne(xa.z); at[3] = (short)bf16_rne(xa.w);
        at[4] = (short)bf16_rne(xb.x); at[5] = (short)bf16_rne(xb.y);
        at[6] = (short)bf16_rne(xb.z); at[7] = (short)bf16_rne(xb.w);
        afr[ks] = __builtin_bit_cast(bf16x8, at);
    }
    __syncthreads();   // W1s staged (vmcnt drain)

    const f32x4 zero4 = {0.f, 0.f, 0.f, 0.f};
    f32x4 acc[8];
    #pragma unroll
    for (int n0 = 0; n0 < 8; ++n0) acc[n0] = zero4;
    #pragma unroll
    for (int ks = 0; ks < 8; ++ks)
        #pragma unroll
        for (int n0 = 0; n0 < 8; ++n0) {
            const int n = n0 * 16 + l15;
            const int b = (ks * 4 + quad) ^ (n & 15);
            const bf16x8 bfr = *(const bf16x8*)(W1s + n * 512 + b * 16);
            acc[n0] = __builtin_amdgcn_mfma_f32_16x16x32_bf16(afr[ks], bfr, acc[n0], 0, 0, 0);
        }

    const int rbase = blockIdx.x * 64 + wave * 16 + quad * 4;
    float dpart[4] = {0.f, 0.f, 0.f, 0.f};
    #pragma unroll
    for (int n0 = 0; n0 < 8; ++n0) {
        const int col = n0 * 16 + l15;
        const float bias = b1[col];
        unsigned short hf[4];
        #pragma unroll
        for (int r = 0; r < 4; ++r) {
            const float hv = acc[n0][r] + bias;
            const unsigned short qb = bf16_rne(hv);
            const float bb = bf16_to_f32(qb);
            dpart[r] += bb * bb;             // dpart unchanged (bf16-based, matches R23)
            h[(size_t)(rbase + r) * EMB + col] = qb;
            hf[r] = f16_bits(hv);            // hT path is f16 (R24)
        }
        ushort4 pk = make_ushort4(hf[0], hf[1], hf[2], hf[3]);
        *(ushort4*)&ldsT[col * 68 + wave * 16 + quad * 4] = pk;
    }
    const float tql = __expf(0.9f * (float)l15 - 10.8f);   // lane's quadrature node
    #pragma unroll
    for (int r = 0; r < 4; ++r) {
        float v = dpart[r];
        v += __shfl_xor(v, 1);
        v += __shfl_xor(v, 2);
        v += __shfl_xor(v, 4);
        v += __shfl_xor(v, 8);
        if (l15 < 10) {
            const float uval = __expf(-tql * v);
            UT [(size_t)l15 * N_TOK + rbase + r] = uval;
            UTh[(size_t)l15 * N_TOK + rbase + r] = f16_bits(uval);
        } else if (l15 == 10) {
            UT [(size_t)10 * N_TOK + rbase + r] = 1.0f;
            UTh[(size_t)10 * N_TOK + rbase + r] = f16_bits(1.0f);
        }
    }
    __syncthreads();
    const int rbase0 = blockIdx.x * 64;
    #pragma unroll
    for (int i = 0; i < 4; ++i) {
        const int slot = i * 256 + threadIdx.x;
        const int c    = slot >> 3;
        const int seg  = slot & 7;
        const ushort4 a0 = *(const ushort4*)&ldsT[c * 68 + seg * 8];
        const ushort4 a1 = *(const ushort4*)&ldsT[c * 68 + seg * 8 + 4];
        ushort4 o[2] = {a0, a1};
        *(uint4*)&hT[(size_t)c * N_TOK + rbase0 + seg * 8] = *(const uint4*)o;
    }
}

// ---------------- k2a: Gram partials G_q = h^T diag(u^q) h, K split 16 x 1024.
// R24: f16 datapath. hT is f16; u pre-converted to f16 (UTh). The A-fragment scale
// becomes au = raw_f16x8 * uth_f16x8 -> 4 v_pk_mul_f16 per frag (was ~36 VALU of
// cvt/mul/pack_trunc per frag). MFMA: mfma_f32_16x16x32_f16 (same rate & layout).
// f16 (11-bit mantissa) is MORE precise than the old bf16+trunc path for h in +-8.
// Structure unchanged from R21/R23: 256-thr blocks, 4 waves (wave=E row-32-group),
// F o-half from blockIdx, grid NQ*KC*2 = 352, LDS dbuf 2x32KB -> 2 blocks/CU.
#define K2A_STAGE(sub_, dst_) do {                                              \
    const int kwin_ = kc * 1024 + (sub_) * 128;                                 \
    _Pragma("unroll")                                                           \
    for (int c = 0; c < 8; ++c) {                                               \
        const int chunk = wave * 8 + c;                                         \
        const int row = chunk * 4 + (lane >> 4);                                \
        const int b = (lane & 15) ^ (row & 15);                                 \
        async_cp16(hT + (size_t)row * N_TOK + kwin_ + b * 8, (dst_) + chunk * 1024); \
    } } while (0)

__global__ __launch_bounds__(256, 2) void k2a_gram(
    const unsigned short* __restrict__ hT, const unsigned short* __restrict__ UTh,
    unsigned short* __restrict__ Gp)
{
    __shared__ __align__(16) unsigned char Rb[2][32768];   // dbuf: 128 rows x 256 B each
    const int lane = threadIdx.x & 63;
    const int wave = threadIdx.x >> 6;    // 0..3 = E row-32-group
    const int quad = lane >> 4;
    const int l15  = lane & 15;
    const int q  = blockIdx.x >> 5;       // 0..10
    const int kc = (blockIdx.x >> 1) & 15;
    const int F  = blockIdx.x & 1;        // o-half (64 cols)
    const int E  = wave;

    const f32x4 zero4 = {0.f, 0.f, 0.f, 0.f};
    f32x4 acc[2][4];
    #pragma unroll
    for (int mt = 0; mt < 2; ++mt)
        #pragma unroll
        for (int nt = 0; nt < 4; ++nt) acc[mt][nt] = zero4;

    K2A_STAGE(0, Rb[0]);
    __syncthreads();   // buf0 staged

    #pragma unroll 1
    for (int sub = 0; sub < 8; ++sub) {
        if (sub < 7) K2A_STAGE(sub + 1, Rb[(sub + 1) & 1]);   // prefetch next window
        const unsigned char* rb = Rb[sub & 1];
        const int kwin = kc * 1024 + sub * 128;

        #pragma unroll
        for (int ks = 0; ks < 4; ++ks) {
            const int kb = kwin + ks * 32 + quad * 8;
            const f16x8v uth = *(const f16x8v*)(UTh + (size_t)q * N_TOK + kb);
            f16x8v au[2];
            #pragma unroll
            for (int mt = 0; mt < 2; ++mt) {
                const int re = E * 32 + mt * 16 + l15;
                const int b = (ks * 4 + quad) ^ (re & 15);
                const f16x8v raw = *(const f16x8v*)(rb + re * 256 + b * 16);
                au[mt] = raw * uth;          // 4x v_pk_mul_f16
            }
            #pragma unroll
            for (int nt = 0; nt < 4; ++nt) {
                const int rf = F * 64 + nt * 16 + l15;
                const int b = (ks * 4 + quad) ^ (rf & 15);
                const f16x8v bfr = *(const f16x8v*)(rb + rf * 256 + b * 16);
                #pragma unroll
                for (int mt = 0; mt < 2; ++mt)
                    acc[mt][nt] = __builtin_amdgcn_mfma_f32_16x16x32_f16(au[mt], bfr, acc[mt][nt], 0, 0, 0);
            }
        }
        if (sub < 7) __syncthreads();   // next buf staged + this buf's reads done
    }

    // Gp bf16: partial quantization 2^-8 RNE before the 16-way sum (same as R23)
    unsigned short* gp = Gp + (size_t)(q * KC + kc) * (EMB * EMB);
    #pragma unroll
    for (int mt = 0; mt < 2; ++mt)
        #pragma unroll
        for (int nt = 0; nt < 4; ++nt)
            #pragma unroll
            for (int r = 0; r < 4; ++r)
                gp[(size_t)(E * 32 + mt * 16 + quad * 4 + r) * EMB + F * 64 + nt * 16 + l15]
                    = bf16_rne(acc[mt][nt][r]);
}

// ---------------- k2b: fused reduce + GWT. Phase 1: block reduces its 16x128 slice
// over the 16 bf16 Gp partials (16B ushort8 loads, cvt+sum in f32) into a swizzled
// bf16 LDS tile. Phase 2: GWT = (2 w_q) * W2T @ Gs^T via MFMA.
__global__ __launch_bounds__(256) void k2b_gwt(
    const unsigned short* __restrict__ Gp, const unsigned short* __restrict__ W2T,
    unsigned short* __restrict__ GWT)
{
    __shared__ __align__(16) unsigned char Gs[16 * 256];   // 16 rows x 256 B, blk b' = b ^ row
    const int q  = blockIdx.x >> 3;     // 0..10
    const int fs = blockIdx.x & 7;      // f-subtile (16 rows)
    const int tid = threadIdx.x;

    // phase 1: reduce KC partials for rows [fs*16, fs*16+16) x 128 cols
    {
        const int fg  = tid >> 4;       // local row 0..15
        const int blk = tid & 15;       // 16B block: 8 consecutive bf16 k-elems
        const unsigned short* src = Gp + (size_t)q * KC * (EMB * EMB)
                                       + (size_t)(fs * 16 + fg) * EMB + blk * 8;
        float s[8] = {0.f, 0.f, 0.f, 0.f, 0.f, 0.f, 0.f, 0.f};
        #pragma unroll
        for (int kc = 0; kc < KC; ++kc) {
            const s16x8 raw = *(const s16x8*)(src + (size_t)kc * (EMB * EMB));
            #pragma unroll
            for (int j = 0; j < 8; ++j)
                s[j] += bf16_to_f32((unsigned short)raw[j]);
        }
        u32x4 w;
        w[0] = pack_rne(s[0], s[1]);
        w[1] = pack_rne(s[2], s[3]);
        w[2] = pack_rne(s[4], s[5]);
        w[3] = pack_rne(s[6], s[7]);
        *(u32x4*)(Gs + fg * 256 + ((blk ^ fg) << 4)) = w;
    }
    __syncthreads();

    // phase 2: GWT = scale * W2T @ Gs^T (MFMA, B-frag rows = G rows fg)
    const int lane = tid & 63;
    const int wave = tid >> 6;
    const int quad = lane >> 4;
    const int l15  = lane & 15;
    const float scale = (q == 10) ? 2.0f * __expf(-10.8f)
                                  : 1.8f * __expf(0.9f * (float)q - 10.8f);  // 2*w_q

    const f32x4 zero4 = {0.f, 0.f, 0.f, 0.f};
    f32x4 acc[2];
    acc[0] = zero4; acc[1] = zero4;
    #pragma unroll
    for (int ks = 0; ks < 4; ++ks) {
        const int b = (ks * 4 + quad) ^ l15;
        const bf16x8 bfr = *(const bf16x8*)(Gs + l15 * 256 + b * 16);
        #pragma unroll
        for (int mt = 0; mt < 2; ++mt) {
            const int o = wave * 32 + mt * 16 + l15;
            const bf16x8 afr = *(const bf16x8*)(W2T + (size_t)o * EMB + ks * 32 + quad * 8);
            acc[mt] = __builtin_amdgcn_mfma_f32_16x16x32_bf16(afr, bfr, acc[mt], 0, 0, 0);
        }
    }
    #pragma unroll
    for (int mt = 0; mt < 2; ++mt)
        #pragma unroll
        for (int r = 0; r < 4; ++r)
            GWT[(size_t)q * (EMB * EMB) + (size_t)(wave * 32 + mt * 16 + quad * 4 + r) * EMB + fs * 16 + l15]
                = bf16_rne(acc[mt][r] * scale);
}

// ---------------- k2c: out[i][o] = relu(b2[o] + sum_q u_i^q * (h_i . GWT_q[o][:]))
// R20: LDS-staged dbuf template, block = 32 i x 64 o, 4 blocks/CU so the NQ serial
// barrier-drain phases overlap across co-resident blocks.
__global__ __launch_bounds__(256, 4) void k2c_apply(
    const unsigned short* __restrict__ h, const unsigned short* __restrict__ GWT,
    const float* __restrict__ UT, const float* __restrict__ b2,
    float* __restrict__ out)
{
    __shared__ __align__(16) unsigned char Gs[2][16384];   // dbuf: 64 o-rows x 256 B
    const int lane = threadIdx.x & 63;
    const int wave = threadIdx.x >> 6;    // 0..3
    const int quad = lane >> 4;
    const int l15  = lane & 15;
    const int ih   = wave & 1;            // i 16-half within the 32-row block
    const int oh   = wave >> 1;           // o 32-half within the 64-col slice
    const int i0   = (blockIdx.x >> 1) * 32;
    const int o0   = (blockIdx.x & 1) * 64;
    const int irow = i0 + ih * 16 + l15;

    bf16x8 araw[4];
    #pragma unroll
    for (int ks = 0; ks < 4; ++ks)
        araw[ks] = *(const bf16x8*)(h + (size_t)irow * EMB + ks * 32 + quad * 8);

    const f32x4 zero4 = {0.f, 0.f, 0.f, 0.f};
    f32x4 acc[2];
    acc[0] = zero4; acc[1] = zero4;

    // stage q=0: 16 chunks x 1KB (4 rows x 256B each), 4 chunks/wave
    #pragma unroll
    for (int c = 0; c < 4; ++c) {
        const int chunk = wave * 4 + c;
        const int row = chunk * 4 + quad;          // local o-row 0..63
        const int b = l15 ^ (row & 15);
        async_cp16(GWT + (size_t)(o0 + row) * EMB + b * 8, &Gs[0][chunk * 1024]);
    }
    #pragma unroll 1
    for (int q = 0; q < NQ; ++q) {
        __syncthreads();   // stage(q) complete (vmcnt drain) + prev compute's reads done
        if (q + 1 < NQ) {
            const unsigned short* src = GWT + (size_t)(q + 1) * (EMB * EMB);
            unsigned char* dst = Gs[(q + 1) & 1];
            #pragma unroll
            for (int c = 0; c < 4; ++c) {
                const int chunk = wave * 4 + c;
                const int row = chunk * 4 + quad;
                const int b = l15 ^ (row & 15);
                async_cp16(src + (size_t)(o0 + row) * EMB + b * 8, dst + chunk * 1024);
            }
        }
        const float4 uq = *(const float4*)(UT + (size_t)q * N_TOK + i0 + ih * 16 + quad * 4);
        const unsigned char* gb = Gs[q & 1];
        #pragma unroll
        for (int nt = 0; nt < 2; ++nt) {
            const int ol = oh * 32 + nt * 16 + l15;   // local o-row 0..63
            f32x4 t = zero4;
            #pragma unroll
            for (int ks = 0; ks < 4; ++ks) {
                const int b = (ks * 4 + quad) ^ (ol & 15);
                const bf16x8 bfr = *(const bf16x8*)(gb + ol * 256 + b * 16);
                t = __builtin_amdgcn_mfma_f32_16x16x32_bf16(araw[ks], bfr, t, 0, 0, 0);
            }
            acc[nt][0] += uq.x * t[0];
            acc[nt][1] += uq.y * t[1];
            acc[nt][2] += uq.z * t[2];
            acc[nt][3] += uq.w * t[3];
        }
    }

    #pragma unroll
    for (int nt = 0; nt < 2; ++nt) {
        const int o = o0 + oh * 32 + nt * 16 + l15;
        const float bias = b2[o];
        #pragma unroll
        for (int r = 0; r < 4; ++r) {
            const float v = acc[nt][r] + bias;
            out[(size_t)(i0 + ih * 16 + quad * 4 + r) * EMB + o] = v > 0.f ? v : 0.f;
        }
    }
}

extern "C" void kernel_launch(void* const* d_in, const int* in_sizes, int n_in,
                              void* d_out, int out_size, void* d_ws, size_t ws_size,
                              hipStream_t stream) {
    const float* x  = (const float*)d_in[0];
    const float* W1 = (const float*)d_in[1];
    const float* b1 = (const float*)d_in[2];
    const float* W2 = (const float*)d_in[3];
    const float* b2 = (const float*)d_in[4];
    float* out = (float*)d_out;

    char* ws = (char*)d_ws;
    // ws (bytes): h 4MB | hT(f16) 4MB | W1T 64KB | W2T 32KB | UT 832KB
    // | Gp bf16 11x16x32KB (5.8MB) | (gap) | GWT 352KB | UTh(f16) 352KB
    unsigned short* h   = (unsigned short*)(ws);
    unsigned short* hT  = (unsigned short*)(ws + 4194304);
    unsigned short* W1T = (unsigned short*)(ws + 8388608);
    unsigned short* W2T = (unsigned short*)(ws + 8454144);
    float*          UT  = (float*)        (ws + 8486912);
    unsigned short* Gp  = (unsigned short*)(ws + 9338880);
    unsigned short* GWT = (unsigned short*)(ws + 23920640);
    unsigned short* UTh = (unsigned short*)(ws + 24379392);

    k0_transpose<<<dim3(64),          dim3(256), 0, stream>>>(W1, W2, W1T, W2T);
    k1_proj     <<<dim3(256),         dim3(256), 0, stream>>>(x, W1T, b1, h, hT, UT, UTh);
    k2a_gram    <<<dim3(NQ * KC * 2), dim3(256), 0, stream>>>(hT, UTh, Gp);
    k2b_gwt     <<<dim3(NQ * 8),      dim3(256), 0, stream>>>(Gp, W2T, GWT);
    k2c_apply   <<<dim3(1024),        dim3(256), 0, stream>>>(h, GWT, UT, b2, out);
}